// Round 4
// baseline (381.666 us; speedup 1.0000x reference)
//
#include <hip/hip_runtime.h>

typedef unsigned short u16;
typedef unsigned int u32;
typedef __bf16 bf16x8 __attribute__((ext_vector_type(8)));
typedef float f32x4 __attribute__((ext_vector_type(4)));

__device__ __forceinline__ u16 f2bf(float f) {
    return __builtin_bit_cast(u16, (__bf16)f);
}
__device__ __forceinline__ u32 pkbf(float a, float b) {
    return (u32)__builtin_bit_cast(u16, (__bf16)a) |
           ((u32)__builtin_bit_cast(u16, (__bf16)b) << 16);
}
__device__ __forceinline__ u32 pku(u16 a, u16 b) {
    return (u32)a | ((u32)b << 16);
}
__device__ __forceinline__ bf16x8 ldb8(const void* p) {
    return __builtin_bit_cast(bf16x8, *(const uint4*)p);
}
__device__ __forceinline__ f32x4 mfma16(bf16x8 a, bf16x8 b, f32x4 c) {
    return __builtin_amdgcn_mfma_f32_16x16x32_bf16(a, b, c, 0, 0, 0);
}
__device__ __forceinline__ float sel4(float4 v, int j) {
    float ab = (j & 1) ? v.y : v.x;
    float cd = (j & 1) ? v.w : v.z;
    return (j & 2) ? cd : ab;
}

// ---------------------------------------------------------------------------
// Weight f32 -> bf16
// ---------------------------------------------------------------------------
__global__ __launch_bounds__(256) void cvt_w(const float* __restrict__ in,
                                             u16* __restrict__ out, int n4) {
    int i = blockIdx.x * 256 + threadIdx.x;
    const int stride = gridDim.x * 256;
    for (; i < n4; i += stride) {
        float4 v = ((const float4*)in)[i];
        ((uint2*)out)[i] = make_uint2(pkbf(v.x, v.y), pkbf(v.z, v.w));
    }
}

// ---------------------------------------------------------------------------
// GroupNorm stats: one block per (batch, group); group data contiguous.
// ---------------------------------------------------------------------------
__global__ __launch_bounds__(256) void gn_stats(const float* __restrict__ in,
                                                float2* __restrict__ stats, int N) {
    const int tid = threadIdx.x;
    const long base = (long)blockIdx.x * N;
    float s = 0.f, s2 = 0.f;
    for (int i = tid * 4; i < N; i += 256 * 4) {
        float4 v = *(const float4*)(in + base + i);
        s += v.x + v.y + v.z + v.w;
        s2 += v.x * v.x + v.y * v.y + v.z * v.z + v.w * v.w;
    }
#pragma unroll
    for (int m = 1; m < 64; m <<= 1) { s += __shfl_xor(s, m); s2 += __shfl_xor(s2, m); }
    __shared__ float ps[4], ps2[4];
    const int w = tid >> 6;
    if ((tid & 63) == 0) { ps[w] = s; ps2[w] = s2; }
    __syncthreads();
    if (tid == 0) {
        float S = ps[0] + ps[1] + ps[2] + ps[3];
        float S2 = ps2[0] + ps2[1] + ps2[2] + ps2[3];
        float mu = S / (float)N;
        float var = S2 / (float)N - mu * mu;
        stats[blockIdx.x] = make_float2(mu, rsqrtf(var + 1e-5f));
    }
}

// ---------------------------------------------------------------------------
// big_gemm v2: out[b,o,n] = sum_c W[o,c]*xform(B[b,c,n]) + bias[o] (+X resid)
// M=512 full, N-tile=64, K=512 in 8 chunks of 64. Double-buffered LDS,
// reg-staged (T14): issue loads -> MFMA -> cvt+ds_write -> 1 barrier/chunk.
// ---------------------------------------------------------------------------
template <bool GN, bool RESID>
__global__ __launch_bounds__(256, 2) void big_gemm(
    const u16* __restrict__ W, const float* __restrict__ B,
    const float2* __restrict__ stats, const float* __restrict__ gamma,
    const float* __restrict__ beta, const float* __restrict__ bias,
    const float* __restrict__ X, float* __restrict__ out) {
    constexpr int K = 512, N = 4096;
    __shared__ u16 Blds[2][64][64];  // [buf][n][k ^ ((n&7)<<3)]
    const int tid = threadIdx.x;
    const int b = blockIdx.z;
    const int n0 = blockIdx.x * 64;
    const int lane = tid & 63, w = tid >> 6;
    const int l16 = lane & 15, g = lane >> 4;
    const float* Bb = B + (long)b * K * N;

    float4 rv[4];
#pragma unroll
    for (int r = 0; r < 4; ++r) {
        int idx = r * 256 + tid;
        int kk = idx >> 4, n4 = (idx & 15) << 2;
        rv[r] = *(const float4*)(Bb + (long)kk * N + n0 + n4);
    }
    // store chunk 0
#pragma unroll
    for (int r = 0; r < 4; ++r) {
        int idx = r * 256 + tid;
        int kk = idx >> 4, n4 = (idx & 15) << 2;
        float4 v = rv[r];
        if (GN) {
            float2 st = stats[b * 32 + (kk >> 4)];
            float gm = gamma[kk], bt = beta[kk];
            v.x = (v.x - st.x) * st.y * gm + bt;
            v.y = (v.y - st.x) * st.y * gm + bt;
            v.z = (v.z - st.x) * st.y * gm + bt;
            v.w = (v.w - st.x) * st.y * gm + bt;
        }
#pragma unroll
        for (int jj = 0; jj < 4; ++jj) {
            int j = (jj + (tid & 3)) & 3;
            int row = n4 + j;
            Blds[0][row][kk ^ ((row & 7) << 3)] = f2bf(sel4(v, j));
        }
    }
    __syncthreads();

    f32x4 acc[8][4] = {};
    for (int c = 0; c < 8; ++c) {
        const int cur = c & 1;
        float4 nv[4];
        if (c < 7) {
            const int k0n = (c + 1) * 64;
#pragma unroll
            for (int r = 0; r < 4; ++r) {
                int idx = r * 256 + tid;
                int kk = idx >> 4, n4 = (idx & 15) << 2;
                nv[r] = *(const float4*)(Bb + (long)(k0n + kk) * N + n0 + n4);
            }
        }
        // compute on buf[cur]
        const int k0 = c * 64;
#pragma unroll
        for (int kk = 0; kk < 2; ++kk) {
            bf16x8 bfr[4];
#pragma unroll
            for (int ni = 0; ni < 4; ++ni) {
                int row = ni * 16 + l16;
                bfr[ni] = ldb8(&Blds[cur][row][(kk * 32 + g * 8) ^ ((row & 7) << 3)]);
            }
#pragma unroll
            for (int mi = 0; mi < 8; ++mi) {
                int arow = w * 128 + mi * 16 + l16;
                bf16x8 afr = ldb8(W + (long)arow * K + k0 + kk * 32 + g * 8);
#pragma unroll
                for (int ni = 0; ni < 4; ++ni)
                    acc[mi][ni] = mfma16(afr, bfr[ni], acc[mi][ni]);
            }
        }
        if (c < 7) {
            const int k0n = (c + 1) * 64;
#pragma unroll
            for (int r = 0; r < 4; ++r) {
                int idx = r * 256 + tid;
                int kk = idx >> 4, n4 = (idx & 15) << 2;
                float4 v = nv[r];
                if (GN) {
                    int kg = k0n + kk;
                    float2 st = stats[b * 32 + (kg >> 4)];
                    float gm = gamma[kg], bt = beta[kg];
                    v.x = (v.x - st.x) * st.y * gm + bt;
                    v.y = (v.y - st.x) * st.y * gm + bt;
                    v.z = (v.z - st.x) * st.y * gm + bt;
                    v.w = (v.w - st.x) * st.y * gm + bt;
                }
#pragma unroll
                for (int jj = 0; jj < 4; ++jj) {
                    int j = (jj + (tid & 3)) & 3;
                    int row = n4 + j;
                    Blds[cur ^ 1][row][kk ^ ((row & 7) << 3)] = f2bf(sel4(v, j));
                }
            }
        }
        __syncthreads();
    }

    const long ob = (long)b * K * N;
#pragma unroll
    for (int mi = 0; mi < 8; ++mi)
#pragma unroll
        for (int i = 0; i < 4; ++i) {
            int row = w * 128 + mi * 16 + g * 4 + i;
            float bs = bias[row];
#pragma unroll
            for (int ni = 0; ni < 4; ++ni) {
                int col = n0 + ni * 16 + l16;
                long off = ob + (long)row * N + col;
                float v = acc[mi][ni][i] + bs;
                if (RESID) v += X[off];
                out[off] = v;
            }
        }
}

// ---------------------------------------------------------------------------
// KV GEMM with fused GroupNorm (M=1024,K=768,N=256). Tile 128x128.
// ---------------------------------------------------------------------------
__global__ __launch_bounds__(256) void gemm_kv(
    const u16* __restrict__ W, const float* __restrict__ act,
    const float2* __restrict__ stats, const float* __restrict__ gamma,
    const float* __restrict__ beta, const float* __restrict__ bias,
    u16* __restrict__ outp, int K, int N, int CPG, long actBS, long outBS) {
    __shared__ u16 Blds[128][40];
    const int tid = threadIdx.x;
    const int b = blockIdx.z;
    const int m0 = blockIdx.y * 128;
    const int n0 = blockIdx.x * 128;
    const int lane = tid & 63;
    const int w = tid >> 6;
    const int wr = w >> 1, wc = w & 1;
    const int l16 = lane & 15, g = lane >> 4;

    const float* actB = act + (long)b * actBS;
    f32x4 acc[4][4] = {};
    const int steps = K / 32;
    for (int s = 0; s < steps; ++s) {
        const int k0 = s * 32;
        __syncthreads();
#pragma unroll
        for (int r = 0; r < 4; ++r) {
            int idx = r * 256 + tid;
            int kk = idx >> 5;
            int n4 = (idx & 31) << 2;
            int kg = k0 + kk;
            float2 st = stats[b * 32 + kg / CPG];
            float gm = gamma[kg], bt = beta[kg];
            float4 v = *(const float4*)(actB + (long)kg * N + n0 + n4);
            Blds[n4 + 0][kk] = f2bf((v.x - st.x) * st.y * gm + bt);
            Blds[n4 + 1][kk] = f2bf((v.y - st.x) * st.y * gm + bt);
            Blds[n4 + 2][kk] = f2bf((v.z - st.x) * st.y * gm + bt);
            Blds[n4 + 3][kk] = f2bf((v.w - st.x) * st.y * gm + bt);
        }
        __syncthreads();
        bf16x8 bfr[4];
#pragma unroll
        for (int ni = 0; ni < 4; ++ni)
            bfr[ni] = ldb8(&Blds[wc * 64 + ni * 16 + l16][g * 8]);
#pragma unroll
        for (int mi = 0; mi < 4; ++mi) {
            int row = m0 + wr * 64 + mi * 16 + l16;
            bf16x8 afr = ldb8(W + (long)row * K + k0 + g * 8);
#pragma unroll
            for (int ni = 0; ni < 4; ++ni)
                acc[mi][ni] = mfma16(afr, bfr[ni], acc[mi][ni]);
        }
    }
#pragma unroll
    for (int mi = 0; mi < 4; ++mi)
#pragma unroll
        for (int i = 0; i < 4; ++i) {
            int row = m0 + wr * 64 + mi * 16 + g * 4 + i;
            float bs = bias[row];
#pragma unroll
            for (int ni = 0; ni < 4; ++ni) {
                int col = n0 + wc * 64 + ni * 16 + l16;
                outp[(long)b * outBS + (long)row * N + col] = f2bf(acc[mi][ni][i] + bs);
            }
        }
}

// ---------------------------------------------------------------------------
// Attention v3: block per (head, 512-t chunk). K,V staged to LDS ONCE
// (64KB, swizzled; V column-permuted so PV needs no cross-lane P moves).
// Then 4 barrier-free iterations; each wave does 2 t-groups of 16.
// ---------------------------------------------------------------------------
__global__ __launch_bounds__(256, 2) void attn_kernel(const float* q,
                                                      const u16* __restrict__ kv,
                                                      float* out) {
    __shared__ u16 kT[256][64];   // [s][d ^ ((s&7)<<3)]
    __shared__ u16 Vp[64][256];   // [d][perm(s) ^ ((d&7)<<3)]
    const int tid = threadIdx.x;
    const int bh = blockIdx.y;
    const int b = bh >> 3, h = bh & 7;
    const int lane = tid & 63, w = tid >> 6;
    const int l16 = lane & 15, g = lane >> 4;

    const long kbase = ((long)(b * 1024 + h * 64)) * 256;
    const long vbase = ((long)(b * 1024 + 512 + h * 64)) * 256;
    const long qb = ((long)(b * 512 + h * 64)) * 4096 + blockIdx.x * 512;

    // ---- stage K transposed (once per block) ----
#pragma unroll
    for (int r = 0; r < 8; ++r) {
        int idx = r * 256 + tid;
        int d = idx >> 5, s8 = idx & 31;
        union { uint4 v; u16 h8[8]; } u;
        u.v = *(const uint4*)(kv + kbase + (long)d * 256 + s8 * 8);
#pragma unroll
        for (int j = 0; j < 8; ++j)
            kT[s8 * 8 + j][d ^ (j << 3)] = u.h8[j];
    }
    // ---- stage V with s->c permutation: c = (f>>1)*32 + g2*8 + (f&1)*4 + i ----
#pragma unroll
    for (int r = 0; r < 8; ++r) {
        int idx = r * 256 + tid;
        int d = idx >> 5, s8 = idx & 31;
        int s0 = s8 * 8;
        union { uint4 v; u16 h8[8]; } u;
        u.v = *(const uint4*)(kv + vbase + (long)d * 256 + s0);
        int f = s0 >> 4, g2 = (s0 >> 2) & 3;
        int cl = ((f >> 1) << 5) + (g2 << 3) + ((f & 1) << 2);
        int sw = (d & 7) << 3;
        *(uint2*)&Vp[d][cl ^ sw] = make_uint2(pku(u.h8[0], u.h8[1]), pku(u.h8[2], u.h8[3]));
        *(uint2*)&Vp[d][(cl + 8) ^ sw] = make_uint2(pku(u.h8[4], u.h8[5]), pku(u.h8[6], u.h8[7]));
    }
    __syncthreads();

    const float aa = 0.015625f * 1.44269504f;  // (1/64)*log2(e)
    for (int it = 0; it < 4; ++it) {
        // ---- q fragments from global (f32 -> bf16) ----
        u32 bqw[2][2][4];
#pragma unroll
        for (int G = 0; G < 2; ++G) {
            int tcol = it * 128 + (w * 2 + G) * 16 + l16;
#pragma unroll
            for (int kk = 0; kk < 2; ++kk) {
                const float* qp = q + qb + tcol + (long)(kk * 32 + g * 8) * 4096;
#pragma unroll
                for (int jp = 0; jp < 4; ++jp)
                    bqw[G][kk][jp] = pkbf(qp[(2 * jp) * 4096], qp[(2 * jp + 1) * 4096]);
            }
        }
        // ---- QK^T ----
        f32x4 sacc[2][16] = {};
#pragma unroll
        for (int kk = 0; kk < 2; ++kk) {
            bf16x8 bq0 = __builtin_bit_cast(bf16x8,
                make_uint4(bqw[0][kk][0], bqw[0][kk][1], bqw[0][kk][2], bqw[0][kk][3]));
            bf16x8 bq1 = __builtin_bit_cast(bf16x8,
                make_uint4(bqw[1][kk][0], bqw[1][kk][1], bqw[1][kk][2], bqw[1][kk][3]));
#pragma unroll
            for (int mi = 0; mi < 16; ++mi) {
                bf16x8 ak = ldb8(&kT[mi * 16 + l16][(kk * 32 + g * 8) ^ ((l16 & 7) << 3)]);
                sacc[0][mi] = mfma16(ak, bq0, sacc[0][mi]);
                sacc[1][mi] = mfma16(ak, bq1, sacc[1][mi]);
            }
        }
        // ---- softmax (unnormalized; defer 1/sum to epilogue) ----
        float inv[2];
        u32 pk[2][16][2];
#pragma unroll
        for (int G = 0; G < 2; ++G) {
            float m = -3e38f;
#pragma unroll
            for (int f = 0; f < 16; ++f)
#pragma unroll
                for (int i = 0; i < 4; ++i) m = fmaxf(m, sacc[G][f][i]);
            m = fmaxf(m, __shfl_xor(m, 16));
            m = fmaxf(m, __shfl_xor(m, 32));
            float m2 = m * aa;
            float sum = 0.f;
#pragma unroll
            for (int f = 0; f < 16; ++f) {
#pragma unroll
                for (int i = 0; i < 4; ++i) {
                    float p = exp2f(fmaf(sacc[G][f][i], aa, -m2));
                    sacc[G][f][i] = p;
                    sum += p;
                }
                pk[G][f][0] = pkbf(sacc[G][f][0], sacc[G][f][1]);
                pk[G][f][1] = pkbf(sacc[G][f][2], sacc[G][f][3]);
            }
            sum += __shfl_xor(sum, 16);
            sum += __shfl_xor(sum, 32);
            inv[G] = 1.0f / sum;
        }
        // ---- PV (V pre-permuted => P fragments are same-lane words) ----
        f32x4 oacc[2][4] = {};
#pragma unroll
        for (int ks = 0; ks < 8; ++ks) {
            bf16x8 bp0 = __builtin_bit_cast(bf16x8,
                make_uint4(pk[0][2 * ks][0], pk[0][2 * ks][1],
                           pk[0][2 * ks + 1][0], pk[0][2 * ks + 1][1]));
            bf16x8 bp1 = __builtin_bit_cast(bf16x8,
                make_uint4(pk[1][2 * ks][0], pk[1][2 * ks][1],
                           pk[1][2 * ks + 1][0], pk[1][2 * ks + 1][1]));
#pragma unroll
            for (int mi = 0; mi < 4; ++mi) {
                bf16x8 av = ldb8(&Vp[mi * 16 + l16][(ks * 32 + g * 8) ^ ((l16 & 7) << 3)]);
                oacc[0][mi] = mfma16(av, bp0, oacc[0][mi]);
                oacc[1][mi] = mfma16(av, bp1, oacc[1][mi]);
            }
        }
        // ---- store O (scaled) ----
#pragma unroll
        for (int G = 0; G < 2; ++G) {
            int tcol = it * 128 + (w * 2 + G) * 16 + l16;
#pragma unroll
            for (int mi = 0; mi < 4; ++mi)
#pragma unroll
                for (int i = 0; i < 4; ++i)
                    out[qb + (long)(mi * 16 + g * 4 + i) * 4096 + tcol] =
                        oacc[G][mi][i] * inv[G];
        }
    }
}

// ---------------------------------------------------------------------------
extern "C" void kernel_launch(void* const* d_in, const int* in_sizes, int n_in,
                              void* d_out, int out_size, void* d_ws, size_t ws_size,
                              hipStream_t stream) {
    const float* x     = (const float*)d_in[0];
    const float* ctx   = (const float*)d_in[1];
    const float* gnx_g = (const float*)d_in[2];
    const float* gnx_b = (const float*)d_in[3];
    const float* gnc_g = (const float*)d_in[4];
    const float* gnc_b = (const float*)d_in[5];
    const float* wq    = (const float*)d_in[6];
    const float* bq    = (const float*)d_in[7];
    const float* wkv   = (const float*)d_in[8];
    const float* bkv   = (const float*)d_in[9];
    const float* wo    = (const float*)d_in[10];
    const float* bo    = (const float*)d_in[11];
    float* out = (float*)d_out;

    char* ws = (char*)d_ws;
    float2* stats_x = (float2*)ws;                    // 2048 B
    float2* stats_c = (float2*)(ws + 2048);           // 2048 B
    u16* wq_bf  = (u16*)(ws + 4096);                  // 512KB
    u16* wkv_bf = (u16*)(ws + 528384);                // 1.5MB
    u16* wo_bf  = (u16*)(ws + 2101248);               // 512KB
    u16* kv     = (u16*)(ws + 2625536);               // 4MB

    cvt_w<<<dim3(256), dim3(256), 0, stream>>>(wq, wq_bf, 512 * 512 / 4);
    cvt_w<<<dim3(256), dim3(256), 0, stream>>>(wkv, wkv_bf, 1024 * 768 / 4);
    cvt_w<<<dim3(256), dim3(256), 0, stream>>>(wo, wo_bf, 512 * 512 / 4);

    gn_stats<<<dim3(256), dim3(256), 0, stream>>>(x, stats_x, 16 * 4096);
    gn_stats<<<dim3(256), dim3(256), 0, stream>>>(ctx, stats_c, 24 * 256);

    // Q = wq @ gn(x) + bq -> d_out (f32)
    big_gemm<true, false><<<dim3(64, 1, 8), dim3(256), 0, stream>>>(
        wq_bf, x, stats_x, gnx_g, gnx_b, bq, nullptr, out);

    // KV = wkv @ gn(ctx) + bkv -> ws (bf16)
    gemm_kv<<<dim3(2, 8, 8), dim3(256), 0, stream>>>(
        wkv_bf, ctx, stats_c, gnc_g, gnc_b, bkv, kv, 768, 256, 24,
        (long)768 * 256, (long)1024 * 256);

    // attention, in place over q in d_out
    attn_kernel<<<dim3(8, 64), dim3(256), 0, stream>>>(out, kv, out);

    // y = x + wo @ attn + bo, in place over d_out
    big_gemm<false, true><<<dim3(64, 1, 8), dim3(256), 0, stream>>>(
        wo_bf, out, nullptr, nullptr, nullptr, bo, x, out);
}

// Round 5
// 317.680 us; speedup vs baseline: 1.2014x; 1.2014x over previous
//
#include <hip/hip_runtime.h>

typedef unsigned short u16;
typedef unsigned int u32;
typedef __bf16 bf16x8 __attribute__((ext_vector_type(8)));
typedef float f32x4 __attribute__((ext_vector_type(4)));

__device__ __forceinline__ u16 f2bf(float f) {
    return __builtin_bit_cast(u16, (__bf16)f);
}
__device__ __forceinline__ u32 pkbf(float a, float b) {
    return (u32)__builtin_bit_cast(u16, (__bf16)a) |
           ((u32)__builtin_bit_cast(u16, (__bf16)b) << 16);
}
__device__ __forceinline__ u32 pku(u16 a, u16 b) {
    return (u32)a | ((u32)b << 16);
}
__device__ __forceinline__ bf16x8 ldb8(const void* p) {
    return __builtin_bit_cast(bf16x8, *(const uint4*)p);
}
__device__ __forceinline__ f32x4 mfma16(bf16x8 a, bf16x8 b, f32x4 c) {
    return __builtin_amdgcn_mfma_f32_16x16x32_bf16(a, b, c, 0, 0, 0);
}

// ---------------------------------------------------------------------------
// Weight f32 -> bf16
// ---------------------------------------------------------------------------
__global__ __launch_bounds__(256) void cvt_w(const float* __restrict__ in,
                                             u16* __restrict__ out, int n4) {
    int i = blockIdx.x * 256 + threadIdx.x;
    const int stride = gridDim.x * 256;
    for (; i < n4; i += stride) {
        float4 v = ((const float4*)in)[i];
        ((uint2*)out)[i] = make_uint2(pkbf(v.x, v.y), pkbf(v.z, v.w));
    }
}

// ---------------------------------------------------------------------------
// GroupNorm stats: one block per (batch, group); group data contiguous.
// ---------------------------------------------------------------------------
__global__ __launch_bounds__(256) void gn_stats(const float* __restrict__ in,
                                                float2* __restrict__ stats, int N) {
    const int tid = threadIdx.x;
    const long base = (long)blockIdx.x * N;
    float s = 0.f, s2 = 0.f;
    for (int i = tid * 4; i < N; i += 256 * 4) {
        float4 v = *(const float4*)(in + base + i);
        s += v.x + v.y + v.z + v.w;
        s2 += v.x * v.x + v.y * v.y + v.z * v.z + v.w * v.w;
    }
#pragma unroll
    for (int m = 1; m < 64; m <<= 1) { s += __shfl_xor(s, m); s2 += __shfl_xor(s2, m); }
    __shared__ float ps[4], ps2[4];
    const int w = tid >> 6;
    if ((tid & 63) == 0) { ps[w] = s; ps2[w] = s2; }
    __syncthreads();
    if (tid == 0) {
        float S = ps[0] + ps[1] + ps[2] + ps[3];
        float S2 = ps2[0] + ps2[1] + ps2[2] + ps2[3];
        float mu = S / (float)N;
        float var = S2 / (float)N - mu * mu;
        stats[blockIdx.x] = make_float2(mu, rsqrtf(var + 1e-5f));
    }
}

// ---------------------------------------------------------------------------
// big_gemm (v1): out[b,o,n] = sum_c W[o,c]*xform(B[b,c,n]) + bias[o] (+X resid)
// M=512 (full), K=512, N-tile=64. 4 waves, wave tile 128M x 64N.
// ---------------------------------------------------------------------------
template <bool GN, bool RESID>
__global__ __launch_bounds__(256, 2) void big_gemm(
    const u16* __restrict__ W, const float* __restrict__ B,
    const float2* __restrict__ stats, const float* __restrict__ gamma,
    const float* __restrict__ beta, const float* __restrict__ bias,
    const float* __restrict__ X, float* __restrict__ out) {
    constexpr int K = 512, N = 4096, CPG = 16;
    __shared__ u16 Blds[64][64];  // [n][k ^ ((n&7)<<3)]
    const int tid = threadIdx.x;
    const int b = blockIdx.z;
    const int n0 = blockIdx.x * 64;
    const int lane = tid & 63, w = tid >> 6;
    const int l16 = lane & 15, g = lane >> 4;
    const float* Bb = B + (long)b * K * N;

    f32x4 acc[8][4] = {};
    for (int c = 0; c < 8; ++c) {
        const int k0 = c * 64;
        __syncthreads();
#pragma unroll
        for (int r = 0; r < 4; ++r) {
            int idx = r * 256 + tid;     // 0..1023
            int kk = idx >> 4;           // 0..63
            int n4 = (idx & 15) << 2;    // 0..60
            int kg = k0 + kk;
            float4 v = *(const float4*)(Bb + (long)kg * N + n0 + n4);
            if (GN) {
                float2 st = stats[b * 32 + kg / CPG];
                float gm = gamma[kg], bt = beta[kg];
                v.x = (v.x - st.x) * st.y * gm + bt;
                v.y = (v.y - st.x) * st.y * gm + bt;
                v.z = (v.z - st.x) * st.y * gm + bt;
                v.w = (v.w - st.x) * st.y * gm + bt;
            }
            float vv[4] = {v.x, v.y, v.z, v.w};
#pragma unroll
            for (int jj = 0; jj < 4; ++jj) {
                int j = (jj + (lane & 3)) & 3;   // rotate to spread store banks
                int row = n4 + j;
                Blds[row][kk ^ ((row & 7) << 3)] = f2bf(vv[j]);
            }
        }
        __syncthreads();
#pragma unroll
        for (int kk = 0; kk < 2; ++kk) {
            bf16x8 bfr[4];
#pragma unroll
            for (int ni = 0; ni < 4; ++ni) {
                int row = ni * 16 + l16;
                bfr[ni] = ldb8(&Blds[row][(kk * 32 + g * 8) ^ ((row & 7) << 3)]);
            }
#pragma unroll
            for (int mi = 0; mi < 8; ++mi) {
                int arow = w * 128 + mi * 16 + l16;
                bf16x8 afr = ldb8(W + (long)arow * K + k0 + kk * 32 + g * 8);
#pragma unroll
                for (int ni = 0; ni < 4; ++ni)
                    acc[mi][ni] = mfma16(afr, bfr[ni], acc[mi][ni]);
            }
        }
    }
    const long ob = (long)b * K * N;
#pragma unroll
    for (int mi = 0; mi < 8; ++mi)
#pragma unroll
        for (int i = 0; i < 4; ++i) {
            int row = w * 128 + mi * 16 + g * 4 + i;
            float bs = bias[row];
#pragma unroll
            for (int ni = 0; ni < 4; ++ni) {
                int col = n0 + ni * 16 + l16;
                long off = ob + (long)row * N + col;
                float v = acc[mi][ni][i] + bs;
                if (RESID) v += X[off];
                out[off] = v;
            }
        }
}

// ---------------------------------------------------------------------------
// KV GEMM with fused GroupNorm (M=1024,K=768,N=256). Tile 128x128.
// ---------------------------------------------------------------------------
__global__ __launch_bounds__(256) void gemm_kv(
    const u16* __restrict__ W, const float* __restrict__ act,
    const float2* __restrict__ stats, const float* __restrict__ gamma,
    const float* __restrict__ beta, const float* __restrict__ bias,
    u16* __restrict__ outp, int K, int N, int CPG, long actBS, long outBS) {
    __shared__ u16 Blds[128][40];
    const int tid = threadIdx.x;
    const int b = blockIdx.z;
    const int m0 = blockIdx.y * 128;
    const int n0 = blockIdx.x * 128;
    const int lane = tid & 63;
    const int w = tid >> 6;
    const int wr = w >> 1, wc = w & 1;
    const int l16 = lane & 15, g = lane >> 4;

    const float* actB = act + (long)b * actBS;
    f32x4 acc[4][4] = {};
    const int steps = K / 32;
    for (int s = 0; s < steps; ++s) {
        const int k0 = s * 32;
        __syncthreads();
#pragma unroll
        for (int r = 0; r < 4; ++r) {
            int idx = r * 256 + tid;
            int kk = idx >> 5;
            int n4 = (idx & 31) << 2;
            int kg = k0 + kk;
            float2 st = stats[b * 32 + kg / CPG];
            float gm = gamma[kg], bt = beta[kg];
            float4 v = *(const float4*)(actB + (long)kg * N + n0 + n4);
            Blds[n4 + 0][kk] = f2bf((v.x - st.x) * st.y * gm + bt);
            Blds[n4 + 1][kk] = f2bf((v.y - st.x) * st.y * gm + bt);
            Blds[n4 + 2][kk] = f2bf((v.z - st.x) * st.y * gm + bt);
            Blds[n4 + 3][kk] = f2bf((v.w - st.x) * st.y * gm + bt);
        }
        __syncthreads();
        bf16x8 bfr[4];
#pragma unroll
        for (int ni = 0; ni < 4; ++ni)
            bfr[ni] = ldb8(&Blds[wc * 64 + ni * 16 + l16][g * 8]);
#pragma unroll
        for (int mi = 0; mi < 4; ++mi) {
            int row = m0 + wr * 64 + mi * 16 + l16;
            bf16x8 afr = ldb8(W + (long)row * K + k0 + g * 8);
#pragma unroll
            for (int ni = 0; ni < 4; ++ni)
                acc[mi][ni] = mfma16(afr, bfr[ni], acc[mi][ni]);
        }
    }
#pragma unroll
    for (int mi = 0; mi < 4; ++mi)
#pragma unroll
        for (int i = 0; i < 4; ++i) {
            int row = m0 + wr * 64 + mi * 16 + g * 4 + i;
            float bs = bias[row];
#pragma unroll
            for (int ni = 0; ni < 4; ++ni) {
                int col = n0 + wc * 64 + ni * 16 + l16;
                outp[(long)b * outBS + (long)row * N + col] = f2bf(acc[mi][ni][i] + bs);
            }
        }
}

// ---------------------------------------------------------------------------
// Attention v4: block per (head, 512-t chunk). K,V staged to LDS ONCE
// (64KB; V column-permuted so PV needs no cross-lane P moves). 8 barrier-free
// iterations; each wave does ONE 16-t group per iteration (low VGPR, no spill).
// ---------------------------------------------------------------------------
__global__ __launch_bounds__(256, 2) void attn_kernel(const float* q,
                                                      const u16* __restrict__ kv,
                                                      float* out) {
    __shared__ u16 kT[256][64];   // [s][d ^ ((s&7)<<3)]
    __shared__ u16 Vp[64][256];   // [d][perm(s) ^ ((d&7)<<3)]
    const int tid = threadIdx.x;
    const int bh = blockIdx.y;
    const int b = bh >> 3, h = bh & 7;
    const int lane = tid & 63, w = tid >> 6;
    const int l16 = lane & 15, g = lane >> 4;

    const long kbase = ((long)(b * 1024 + h * 64)) * 256;
    const long vbase = ((long)(b * 1024 + 512 + h * 64)) * 256;
    const long qb = ((long)(b * 512 + h * 64)) * 4096 + blockIdx.x * 512;

    // ---- stage K transposed (once per block) ----
#pragma unroll
    for (int r = 0; r < 8; ++r) {
        int idx = r * 256 + tid;
        int d = idx >> 5, s8 = idx & 31;
        union { uint4 v; u16 h8[8]; } u;
        u.v = *(const uint4*)(kv + kbase + (long)d * 256 + s8 * 8);
#pragma unroll
        for (int j = 0; j < 8; ++j)
            kT[s8 * 8 + j][d ^ (j << 3)] = u.h8[j];
    }
    // ---- stage V with s->c permutation: c = (f>>1)*32 + g2*8 + (f&1)*4 + i ----
#pragma unroll
    for (int r = 0; r < 8; ++r) {
        int idx = r * 256 + tid;
        int d = idx >> 5, s8 = idx & 31;
        int s0 = s8 * 8;
        union { uint4 v; u16 h8[8]; } u;
        u.v = *(const uint4*)(kv + vbase + (long)d * 256 + s0);
        int f = s0 >> 4, g2 = (s0 >> 2) & 3;
        int cl = ((f >> 1) << 5) + (g2 << 3) + ((f & 1) << 2);
        int sw = (d & 7) << 3;
        *(uint2*)&Vp[d][cl ^ sw] = make_uint2(pku(u.h8[0], u.h8[1]), pku(u.h8[2], u.h8[3]));
        *(uint2*)&Vp[d][(cl + 8) ^ sw] = make_uint2(pku(u.h8[4], u.h8[5]), pku(u.h8[6], u.h8[7]));
    }
    __syncthreads();

    const float aa = 0.015625f * 1.44269504f;  // (1/64)*log2(e)
    for (int it = 0; it < 8; ++it) {
        const int tcol = it * 64 + w * 16 + l16;
        // ---- q fragment from global (f32 -> bf16) ----
        u32 bqw[2][4];
#pragma unroll
        for (int kk = 0; kk < 2; ++kk) {
            const float* qp = q + qb + tcol + (long)(kk * 32 + g * 8) * 4096;
#pragma unroll
            for (int jp = 0; jp < 4; ++jp)
                bqw[kk][jp] = pkbf(qp[(2 * jp) * 4096], qp[(2 * jp + 1) * 4096]);
        }
        // ---- QK^T ----
        f32x4 sacc[16] = {};
#pragma unroll
        for (int kk = 0; kk < 2; ++kk) {
            bf16x8 bq_ = __builtin_bit_cast(bf16x8,
                make_uint4(bqw[kk][0], bqw[kk][1], bqw[kk][2], bqw[kk][3]));
#pragma unroll
            for (int mi = 0; mi < 16; ++mi) {
                bf16x8 ak = ldb8(&kT[mi * 16 + l16][(kk * 32 + g * 8) ^ ((l16 & 7) << 3)]);
                sacc[mi] = mfma16(ak, bq_, sacc[mi]);
            }
        }
        // ---- softmax over s (64 in-thread + xor16/32), unnormalized ----
        float m = -3e38f;
#pragma unroll
        for (int f = 0; f < 16; ++f)
#pragma unroll
            for (int i = 0; i < 4; ++i) m = fmaxf(m, sacc[f][i]);
        m = fmaxf(m, __shfl_xor(m, 16));
        m = fmaxf(m, __shfl_xor(m, 32));
        float m2 = m * aa;
        float sum = 0.f;
#pragma unroll
        for (int f = 0; f < 16; ++f)
#pragma unroll
            for (int i = 0; i < 4; ++i) {
                float p = exp2f(fmaf(sacc[f][i], aa, -m2));
                sacc[f][i] = p;
                sum += p;
            }
        sum += __shfl_xor(sum, 16);
        sum += __shfl_xor(sum, 32);
        const float inv = 1.0f / sum;
        // ---- PV (V pre-permuted => P fragments are same-lane packed words) ----
        f32x4 oacc[4] = {};
#pragma unroll
        for (int ks = 0; ks < 8; ++ks) {
            bf16x8 bp = __builtin_bit_cast(bf16x8,
                make_uint4(pkbf(sacc[2 * ks][0], sacc[2 * ks][1]),
                           pkbf(sacc[2 * ks][2], sacc[2 * ks][3]),
                           pkbf(sacc[2 * ks + 1][0], sacc[2 * ks + 1][1]),
                           pkbf(sacc[2 * ks + 1][2], sacc[2 * ks + 1][3])));
#pragma unroll
            for (int mi = 0; mi < 4; ++mi) {
                bf16x8 av = ldb8(&Vp[mi * 16 + l16][(ks * 32 + g * 8) ^ ((l16 & 7) << 3)]);
                oacc[mi] = mfma16(av, bp, oacc[mi]);
            }
        }
        // ---- store O (scaled) ----
#pragma unroll
        for (int mi = 0; mi < 4; ++mi)
#pragma unroll
            for (int i = 0; i < 4; ++i)
                out[qb + (long)(mi * 16 + g * 4 + i) * 4096 + tcol] = oacc[mi][i] * inv;
    }
}

// ---------------------------------------------------------------------------
extern "C" void kernel_launch(void* const* d_in, const int* in_sizes, int n_in,
                              void* d_out, int out_size, void* d_ws, size_t ws_size,
                              hipStream_t stream) {
    const float* x     = (const float*)d_in[0];
    const float* ctx   = (const float*)d_in[1];
    const float* gnx_g = (const float*)d_in[2];
    const float* gnx_b = (const float*)d_in[3];
    const float* gnc_g = (const float*)d_in[4];
    const float* gnc_b = (const float*)d_in[5];
    const float* wq    = (const float*)d_in[6];
    const float* bq    = (const float*)d_in[7];
    const float* wkv   = (const float*)d_in[8];
    const float* bkv   = (const float*)d_in[9];
    const float* wo    = (const float*)d_in[10];
    const float* bo    = (const float*)d_in[11];
    float* out = (float*)d_out;

    char* ws = (char*)d_ws;
    float2* stats_x = (float2*)ws;                    // 2048 B
    float2* stats_c = (float2*)(ws + 2048);           // 2048 B
    u16* wq_bf  = (u16*)(ws + 4096);                  // 512KB
    u16* wkv_bf = (u16*)(ws + 528384);                // 1.5MB
    u16* wo_bf  = (u16*)(ws + 2101248);               // 512KB
    u16* kv     = (u16*)(ws + 2625536);               // 4MB

    cvt_w<<<dim3(256), dim3(256), 0, stream>>>(wq, wq_bf, 512 * 512 / 4);
    cvt_w<<<dim3(256), dim3(256), 0, stream>>>(wkv, wkv_bf, 1024 * 768 / 4);
    cvt_w<<<dim3(256), dim3(256), 0, stream>>>(wo, wo_bf, 512 * 512 / 4);

    gn_stats<<<dim3(256), dim3(256), 0, stream>>>(x, stats_x, 16 * 4096);
    gn_stats<<<dim3(256), dim3(256), 0, stream>>>(ctx, stats_c, 24 * 256);

    // Q = wq @ gn(x) + bq -> d_out (f32)
    big_gemm<true, false><<<dim3(64, 1, 8), dim3(256), 0, stream>>>(
        wq_bf, x, stats_x, gnx_g, gnx_b, bq, nullptr, out);

    // KV = wkv @ gn(ctx) + bkv -> ws (bf16)
    gemm_kv<<<dim3(2, 8, 8), dim3(256), 0, stream>>>(
        wkv_bf, ctx, stats_c, gnc_g, gnc_b, bkv, kv, 768, 256, 24,
        (long)768 * 256, (long)1024 * 256);

    // attention, in place over q in d_out
    attn_kernel<<<dim3(8, 64), dim3(256), 0, stream>>>(out, kv, out);

    // y = x + wo @ attn + bo, in place over d_out
    big_gemm<false, true><<<dim3(64, 1, 8), dim3(256), 0, stream>>>(
        wo_bf, out, nullptr, nullptr, nullptr, bo, x, out);
}